// Round 6
// baseline (379.909 us; speedup 1.0000x reference)
//
#include <hip/hip_runtime.h>
#include <hip/hip_fp16.h>

#define IN_F 128
#define OUT_F 64
#define BSH   7        // 128 nodes per bucket
#define BNODES 128
#define NBK   782      // ceil(100000 / 128)
#define ACAP  1024     // slots per bucket (mean 767, +9.3 sigma)
#define CHUNK 4096     // edges per bin block
#define KPF  136       // Fh k-pitch (bf16 elems)
#define KPW  144       // Wt k-pitch (bf16 elems)

using short8  = __attribute__((ext_vector_type(8))) short;
using float4v = __attribute__((ext_vector_type(4))) float;

static __device__ inline unsigned short f2bf(float x) {
    union { float f; unsigned u; } v; v.f = x;
    unsigned r = (v.u + 0x7fffu + ((v.u >> 16) & 1u)) >> 16;  // RN-even
    return (unsigned short)r;
}

// ---- pass 1: bin edges by dst-bucket (src | dlocal<<20) and src-bucket (src)
// LDS-aggregated cursor reservation: ~1500 global atomics/block, not per-edge.
__global__ __launch_bounds__(256) void bin_kernel(
    const int* __restrict__ src, const int* __restrict__ dst,
    int* __restrict__ gcur_d, int* __restrict__ gcur_s,
    unsigned* __restrict__ bkt_d, unsigned* __restrict__ bkt_s, int E)
{
    __shared__ int hd[NBK], hs[NBK], based[NBK], bases[NBK];
    const int tid = threadIdx.x;
    const int e0  = blockIdx.x * CHUNK;

    for (int i = tid; i < NBK; i += 256) { hd[i] = 0; hs[i] = 0; }
    __syncthreads();

    int sv[16], dv[16];
    #pragma unroll
    for (int j = 0; j < 16; ++j) {
        int i = e0 + j * 256 + tid;          // coalesced
        if (i < E) { sv[j] = src[i]; dv[j] = dst[i]; }
        else       { sv[j] = -1;     dv[j] = -1; }
    }
    #pragma unroll
    for (int j = 0; j < 16; ++j) {
        if (dv[j] >= 0) {
            atomicAdd(&hd[dv[j] >> BSH], 1);
            atomicAdd(&hs[sv[j] >> BSH], 1);
        }
    }
    __syncthreads();

    for (int i = tid; i < NBK; i += 256) {
        int cd = hd[i], cs = hs[i];
        based[i] = cd ? atomicAdd(&gcur_d[i], cd) : 0;
        bases[i] = cs ? atomicAdd(&gcur_s[i], cs) : 0;
        hd[i] = 0; hs[i] = 0;                // reuse as local cursors
    }
    __syncthreads();

    #pragma unroll
    for (int j = 0; j < 16; ++j) {
        if (dv[j] >= 0) {
            int bd = dv[j] >> BSH;
            int pd = atomicAdd(&hd[bd], 1) + based[bd];
            if (pd < ACAP)
                bkt_d[(size_t)bd * ACAP + pd] =
                    (unsigned)sv[j] | ((unsigned)(dv[j] & (BNODES - 1)) << 20);
            int bs = sv[j] >> BSH;
            int ps = atomicAdd(&hs[bs], 1) + bases[bs];
            if (ps < ACAP) bkt_s[(size_t)bs * ACAP + ps] = (unsigned)sv[j];
        }
    }
}

// ---- pass 2: per-bucket src histogram -> outdeg ----------------------------
__global__ __launch_bounds__(256) void outdeg_kernel(
    const unsigned* __restrict__ bkt_s, const int* __restrict__ gcur_s,
    int* __restrict__ outdeg, int n)
{
    __shared__ int hist[BNODES];
    const int b = blockIdx.x, tid = threadIdx.x;
    if (tid < BNODES) hist[tid] = 0;
    __syncthreads();
    const int m = min(gcur_s[b], ACAP);
    for (int i = tid; i < m; i += 256)
        atomicAdd(&hist[bkt_s[(size_t)b * ACAP + i] & (BNODES - 1)], 1);
    __syncthreads();
    int node = b * BNODES + tid;
    if (tid < BNODES && node < n) outdeg[node] = hist[tid];
}

// ---- fused GEMM + norm_src via bf16 MFMA (unchanged from R5, verified) -----
__global__ __launch_bounds__(256) void gemm_norm_kernel(
    const float* __restrict__ feat,
    const float* __restrict__ W,
    const int*   __restrict__ outdeg,
    __half* __restrict__ h,
    int n)
{
    __shared__ unsigned short Fh[128 * KPF];  // 34816 B
    __shared__ unsigned short Wt[64 * KPW];   // 18432 B

    const int tid  = threadIdx.x;
    const int row0 = blockIdx.x * 128;

    {
        const float4* W4 = (const float4*)W;
        #pragma unroll
        for (int it = 0; it < 8; ++it) {
            int i4 = it * 256 + tid;
            int k  = i4 >> 4;
            int c4 = (i4 & 15) * 4;
            float4 wv = W4[i4];
            Wt[(c4 + 0) * KPW + k] = f2bf(wv.x);
            Wt[(c4 + 1) * KPW + k] = f2bf(wv.y);
            Wt[(c4 + 2) * KPW + k] = f2bf(wv.z);
            Wt[(c4 + 3) * KPW + k] = f2bf(wv.w);
        }
    }
    {
        const float4* F4 = (const float4*)feat;
        #pragma unroll
        for (int it = 0; it < 16; ++it) {
            int i4 = it * 256 + tid;
            int r  = i4 >> 5;
            int c4 = (i4 & 31) * 4;
            int gr = row0 + r; if (gr >= n) gr = n - 1;
            float4 v = F4[(long)gr * 32 + (i4 & 31)];
            ushort4 u;
            u.x = f2bf(v.x); u.y = f2bf(v.y); u.z = f2bf(v.z); u.w = f2bf(v.w);
            *(ushort4*)&Fh[r * KPF + c4] = u;
        }
    }
    __syncthreads();

    const int w  = tid >> 6;
    const int l  = tid & 63;
    const int ml = l & 15;
    const int q  = l >> 4;

    float4v acc[2][4];
    #pragma unroll
    for (int rt = 0; rt < 2; ++rt)
        #pragma unroll
        for (int ct = 0; ct < 4; ++ct)
            acc[rt][ct] = (float4v){0.f, 0.f, 0.f, 0.f};

    #pragma unroll
    for (int ks = 0; ks < 4; ++ks) {
        const int ko = ks * 32 + q * 8;
        short8 a0 = *(const short8*)&Fh[(w * 32 +  0 + ml) * KPF + ko];
        short8 a1 = *(const short8*)&Fh[(w * 32 + 16 + ml) * KPF + ko];
        short8 b0 = *(const short8*)&Wt[( 0 + ml) * KPW + ko];
        short8 b1 = *(const short8*)&Wt[(16 + ml) * KPW + ko];
        short8 b2 = *(const short8*)&Wt[(32 + ml) * KPW + ko];
        short8 b3 = *(const short8*)&Wt[(48 + ml) * KPW + ko];
        acc[0][0] = __builtin_amdgcn_mfma_f32_16x16x32_bf16(a0, b0, acc[0][0], 0, 0, 0);
        acc[0][1] = __builtin_amdgcn_mfma_f32_16x16x32_bf16(a0, b1, acc[0][1], 0, 0, 0);
        acc[0][2] = __builtin_amdgcn_mfma_f32_16x16x32_bf16(a0, b2, acc[0][2], 0, 0, 0);
        acc[0][3] = __builtin_amdgcn_mfma_f32_16x16x32_bf16(a0, b3, acc[0][3], 0, 0, 0);
        acc[1][0] = __builtin_amdgcn_mfma_f32_16x16x32_bf16(a1, b0, acc[1][0], 0, 0, 0);
        acc[1][1] = __builtin_amdgcn_mfma_f32_16x16x32_bf16(a1, b1, acc[1][1], 0, 0, 0);
        acc[1][2] = __builtin_amdgcn_mfma_f32_16x16x32_bf16(a1, b2, acc[1][2], 0, 0, 0);
        acc[1][3] = __builtin_amdgcn_mfma_f32_16x16x32_bf16(a1, b3, acc[1][3], 0, 0, 0);
    }

    #pragma unroll
    for (int rt = 0; rt < 2; ++rt) {
        #pragma unroll
        for (int reg = 0; reg < 4; ++reg) {
            int row = row0 + w * 32 + rt * 16 + q * 4 + reg;
            if (row < n) {
                float ns = rsqrtf(fmaxf((float)outdeg[row], 1.0f));
                #pragma unroll
                for (int ct = 0; ct < 4; ++ct)
                    h[(long)row * OUT_F + ct * 16 + ml] = __float2half(acc[rt][ct][reg] * ns);
            }
        }
    }
}

// ---- pass 3: per-bucket LDS accumulation (replaces CSR sort + gather) ------
// block b owns dst nodes [b*128, b*128+128); accum[128][64] fp32 in LDS.
// half-wave per edge, half2 per lane, 4-deep unroll for MLP.
__global__ __launch_bounds__(256) void agg_kernel(
    const unsigned* __restrict__ bkt_d, const int* __restrict__ gcur_d,
    const __half* __restrict__ h, float* __restrict__ out, int n)
{
    __shared__ float accum[BNODES * OUT_F];   // 32 KB
    __shared__ int   cnt[BNODES];
    const int b   = blockIdx.x;
    const int tid = threadIdx.x;

    for (int i = tid; i < BNODES * 16; i += 256)
        *(float4*)&accum[i * 4] = make_float4(0.f, 0.f, 0.f, 0.f);
    if (tid < BNODES) cnt[tid] = 0;
    __syncthreads();

    const int m  = min(gcur_d[b], ACAP);
    const int l  = tid & 63;
    const int wv = tid >> 6;
    const int eh = l >> 5;          // half-wave id
    const int c2 = l & 31;          // column pair
    const unsigned* bp = bkt_d + (size_t)b * ACAP;

    int i = wv * 2 + eh;            // 8 edges in flight per block-iter
    for (; i + 24 < m; i += 32) {   // 4-deep unroll per half-wave
        unsigned v0 = bp[i], v1 = bp[i + 8], v2 = bp[i + 16], v3 = bp[i + 24];
        int s0 = v0 & 0xFFFFF, s1 = v1 & 0xFFFFF, s2 = v2 & 0xFFFFF, s3 = v3 & 0xFFFFF;
        __half2 q0 = *(const __half2*)&h[(long)s0 * OUT_F + 2 * c2];
        __half2 q1 = *(const __half2*)&h[(long)s1 * OUT_F + 2 * c2];
        __half2 q2 = *(const __half2*)&h[(long)s2 * OUT_F + 2 * c2];
        __half2 q3 = *(const __half2*)&h[(long)s3 * OUT_F + 2 * c2];
        float2 f0 = __half22float2(q0), f1 = __half22float2(q1);
        float2 f2 = __half22float2(q2), f3 = __half22float2(q3);
        int d0 = v0 >> 20, d1 = v1 >> 20, d2 = v2 >> 20, d3 = v3 >> 20;
        atomicAdd(&accum[d0 * OUT_F + 2 * c2],     f0.x);
        atomicAdd(&accum[d0 * OUT_F + 2 * c2 + 1], f0.y);
        atomicAdd(&accum[d1 * OUT_F + 2 * c2],     f1.x);
        atomicAdd(&accum[d1 * OUT_F + 2 * c2 + 1], f1.y);
        atomicAdd(&accum[d2 * OUT_F + 2 * c2],     f2.x);
        atomicAdd(&accum[d2 * OUT_F + 2 * c2 + 1], f2.y);
        atomicAdd(&accum[d3 * OUT_F + 2 * c2],     f3.x);
        atomicAdd(&accum[d3 * OUT_F + 2 * c2 + 1], f3.y);
        if (c2 == 0) {
            atomicAdd(&cnt[d0], 1); atomicAdd(&cnt[d1], 1);
            atomicAdd(&cnt[d2], 1); atomicAdd(&cnt[d3], 1);
        }
    }
    for (; i < m; i += 8) {
        unsigned v = bp[i];
        int s = v & 0xFFFFF, d = v >> 20;
        __half2 q = *(const __half2*)&h[(long)s * OUT_F + 2 * c2];
        float2 f = __half22float2(q);
        atomicAdd(&accum[d * OUT_F + 2 * c2],     f.x);
        atomicAdd(&accum[d * OUT_F + 2 * c2 + 1], f.y);
        if (c2 == 0) atomicAdd(&cnt[d], 1);
    }
    __syncthreads();

    // coalesced writeout with rsqrt(indeg) folded in
    for (int i4 = tid; i4 < BNODES * 16; i4 += 256) {
        int r = i4 >> 4;
        int node = b * BNODES + r;
        if (node < n) {
            float nd = rsqrtf(fmaxf((float)cnt[r], 1.0f));
            float4 v = *(float4*)&accum[i4 * 4];
            v.x *= nd; v.y *= nd; v.z *= nd; v.w *= nd;
            *(float4*)&out[(long)node * OUT_F + (i4 & 15) * 4] = v;
        }
    }
}

extern "C" void kernel_launch(void* const* d_in, const int* in_sizes, int n_in,
                              void* d_out, int out_size, void* d_ws, size_t ws_size,
                              hipStream_t stream) {
    const float* feat = (const float*)d_in[0];
    const float* W    = (const float*)d_in[1];
    const int*   src  = (const int*)d_in[2];
    const int*   dst  = (const int*)d_in[3];
    float* out = (float*)d_out;

    const int n = in_sizes[0] / IN_F;     // 100000
    const int E = in_sizes[2];            // 600000

    // ---- workspace layout (~16.4 MB) ----
    char* wsb = (char*)d_ws;
    int* gcur_d = (int*)wsb;                       // NBK (pad 784)
    int* gcur_s = gcur_d + 784;                    // NBK
    int* outdeg = gcur_s + 784;                    // n
    size_t pos = (((size_t)(2 * 784 + n)) * 4 + 15) & ~(size_t)15;
    unsigned* bkt_d = (unsigned*)(wsb + pos);      // NBK*ACAP u32 (3.2 MB)
    pos = (pos + (size_t)NBK * ACAP * 4 + 15) & ~(size_t)15;
    unsigned* bkt_s = (unsigned*)(wsb + pos);      // NBK*ACAP u32 (3.2 MB)
    __half*   h     = (__half*)(wsb + pos);        // n*64 fp16 (12.8 MB) — aliases
                                                   // bkt_s (consumed by outdeg first)

    hipMemsetAsync(gcur_d, 0, 2 * 784 * sizeof(int), stream);

    bin_kernel<<<(E + CHUNK - 1) / CHUNK, 256, 0, stream>>>(src, dst, gcur_d, gcur_s,
                                                            bkt_d, bkt_s, E);
    outdeg_kernel<<<NBK, 256, 0, stream>>>(bkt_s, gcur_s, outdeg, n);
    gemm_norm_kernel<<<(n + 127) / 128, 256, 0, stream>>>(feat, W, outdeg, h, n);
    agg_kernel<<<NBK, 256, 0, stream>>>(bkt_d, gcur_d, h, out, n);
}

// Round 7
// 166.077 us; speedup vs baseline: 2.2875x; 2.2875x over previous
//
#include <hip/hip_runtime.h>
#include <hip/hip_fp16.h>

#define IN_F 128
#define OUT_F 64
#define NB   256      // node-range buckets (512 nodes each)
#define BSH  9
#define CAP  3840     // slots per bucket (mean 2344, +31 sigma) — proven R4/R5
#define CHUNK 2048    // edges per bin block (293 blocks -> spread LDS-atomic load)
#define KPF  136      // Fh k-pitch (bf16 elems)
#define KPW  144      // Wt k-pitch (bf16 elems)

using short8  = __attribute__((ext_vector_type(8))) short;
using float4v = __attribute__((ext_vector_type(4))) float;

static __device__ inline unsigned short f2bf(float x) {
    union { float f; unsigned u; } v; v.f = x;
    unsigned r = (v.u + 0x7fffu + ((v.u >> 16) & 1u)) >> 16;  // RN-even
    return (unsigned short)r;
}

// ---- pass 1: bin edges by dst-range (u32: src | dlocal<<17) and src-range (u16 slocal)
// LDS-aggregated run reservation: ~512 global atomics per block, 4 LDS lane-atomics/edge.
__global__ __launch_bounds__(256) void bin_kernel(
    const int* __restrict__ src, const int* __restrict__ dst,
    int* __restrict__ gcur_d, int* __restrict__ gcur_s,
    unsigned* __restrict__ bkt_d, unsigned short* __restrict__ bkt_s, int E)
{
    __shared__ int hd[NB], hs[NB], based[NB], bases[NB];
    const int tid = threadIdx.x;
    const int e0  = blockIdx.x * CHUNK;

    hd[tid] = 0; hs[tid] = 0;
    __syncthreads();

    int sv[8], dv[8];
    #pragma unroll
    for (int j = 0; j < 8; ++j) {
        int i = e0 + j * 256 + tid;          // coalesced
        if (i < E) { sv[j] = src[i]; dv[j] = dst[i]; }
        else       { sv[j] = -1;     dv[j] = -1; }
    }
    #pragma unroll
    for (int j = 0; j < 8; ++j) {
        if (dv[j] >= 0) {
            atomicAdd(&hd[dv[j] >> BSH], 1);
            atomicAdd(&hs[sv[j] >> BSH], 1);
        }
    }
    __syncthreads();

    int cd = hd[tid], cs = hs[tid];
    based[tid] = cd ? atomicAdd(&gcur_d[tid], cd) : 0;
    bases[tid] = cs ? atomicAdd(&gcur_s[tid], cs) : 0;
    hd[tid] = 0; hs[tid] = 0;                // reuse as local cursors
    __syncthreads();

    #pragma unroll
    for (int j = 0; j < 8; ++j) {
        if (dv[j] >= 0) {
            int bd = dv[j] >> BSH;
            int pd = atomicAdd(&hd[bd], 1) + based[bd];
            if (pd < CAP)
                bkt_d[(size_t)bd * CAP + pd] =
                    (unsigned)sv[j] | ((unsigned)(dv[j] & 511) << 17);  // src<2^17
            int bs = sv[j] >> BSH;
            int ps = atomicAdd(&hs[bs], 1) + bases[bs];
            if (ps < CAP) bkt_s[(size_t)bs * CAP + ps] = (unsigned short)(sv[j] & 511);
        }
    }
}

// ---- exclusive scan of the 256 dst-bucket sizes -> bbase --------------------
__global__ __launch_bounds__(256) void base_kernel(const int* __restrict__ gcur_d,
                                                   int* __restrict__ bbase)
{
    __shared__ int sc[256];
    int tid = threadIdx.x;
    int v = gcur_d[tid];
    sc[tid] = v; __syncthreads();
    for (int o = 1; o < 256; o <<= 1) {
        int t = (tid >= o) ? sc[tid - o] : 0;
        __syncthreads();
        sc[tid] += t;
        __syncthreads();
    }
    bbase[tid] = sc[tid] - v;
}

// ---- per-bucket src histogram -> outdeg ------------------------------------
__global__ __launch_bounds__(256) void outdeg_kernel(
    const unsigned short* __restrict__ bkt_s, const int* __restrict__ gcur_s,
    int* __restrict__ outdeg, int n)
{
    __shared__ int hist[512];
    const int b = blockIdx.x, tid = threadIdx.x;
    hist[tid] = 0; hist[tid + 256] = 0;
    __syncthreads();
    const int m = min(gcur_s[b], CAP);
    for (int i = tid; i < m; i += 256)
        atomicAdd(&hist[bkt_s[(size_t)b * CAP + i]], 1);
    __syncthreads();
    int node = b * 512 + tid;
    if (node < n) outdeg[node] = hist[tid];
    node += 256;
    if (node < n) outdeg[node] = hist[tid + 256];
}

// ---- per-bucket counting sort -> off[], ebuf[] ------------------------------
__global__ __launch_bounds__(256) void csr_kernel(
    const unsigned* __restrict__ bkt_d, const int* __restrict__ gcur_d,
    const int* __restrict__ bbase, int* __restrict__ off, int* __restrict__ ebuf)
{
    __shared__ int hist[512], curs[512], sc[256];
    __shared__ int sbuf[CAP];
    const int b = blockIdx.x, tid = threadIdx.x;
    const int cnt  = min(gcur_d[b], CAP);
    const int base = bbase[b];

    hist[tid] = 0; hist[tid + 256] = 0;
    __syncthreads();
    for (int i = tid; i < cnt; i += 256)
        atomicAdd(&hist[bkt_d[(size_t)b * CAP + i] >> 17], 1);
    __syncthreads();

    int a0 = hist[2 * tid], a1 = hist[2 * tid + 1];
    int psum = a0 + a1;
    sc[tid] = psum; __syncthreads();
    for (int o = 1; o < 256; o <<= 1) {
        int t = (tid >= o) ? sc[tid - o] : 0;
        __syncthreads();
        sc[tid] += t;
        __syncthreads();
    }
    int excl = sc[tid] - psum;
    curs[2 * tid]     = excl;
    curs[2 * tid + 1] = excl + a0;
    off[b * 512 + 2 * tid]     = base + excl;
    off[b * 512 + 2 * tid + 1] = base + excl + a0;
    __syncthreads();

    for (int i = tid; i < cnt; i += 256) {
        unsigned e = bkt_d[(size_t)b * CAP + i];
        int p = atomicAdd(&curs[e >> 17], 1);
        sbuf[p] = (int)(e & 0x1FFFFu);
    }
    __syncthreads();
    for (int i = tid; i < cnt; i += 256)
        ebuf[base + i] = sbuf[i];
}

// ---- fused GEMM + norm_src via bf16 MFMA (verified R5) ----------------------
__global__ __launch_bounds__(256) void gemm_norm_kernel(
    const float* __restrict__ feat,
    const float* __restrict__ W,
    const int*   __restrict__ outdeg,
    __half* __restrict__ h,
    int n)
{
    __shared__ unsigned short Fh[128 * KPF];  // 34816 B
    __shared__ unsigned short Wt[64 * KPW];   // 18432 B

    const int tid  = threadIdx.x;
    const int row0 = blockIdx.x * 128;

    {
        const float4* W4 = (const float4*)W;
        #pragma unroll
        for (int it = 0; it < 8; ++it) {
            int i4 = it * 256 + tid;
            int k  = i4 >> 4;
            int c4 = (i4 & 15) * 4;
            float4 wv = W4[i4];
            Wt[(c4 + 0) * KPW + k] = f2bf(wv.x);
            Wt[(c4 + 1) * KPW + k] = f2bf(wv.y);
            Wt[(c4 + 2) * KPW + k] = f2bf(wv.z);
            Wt[(c4 + 3) * KPW + k] = f2bf(wv.w);
        }
    }
    {
        const float4* F4 = (const float4*)feat;
        #pragma unroll
        for (int it = 0; it < 16; ++it) {
            int i4 = it * 256 + tid;
            int r  = i4 >> 5;
            int c4 = (i4 & 31) * 4;
            int gr = row0 + r; if (gr >= n) gr = n - 1;
            float4 v = F4[(long)gr * 32 + (i4 & 31)];
            ushort4 u;
            u.x = f2bf(v.x); u.y = f2bf(v.y); u.z = f2bf(v.z); u.w = f2bf(v.w);
            *(ushort4*)&Fh[r * KPF + c4] = u;
        }
    }
    __syncthreads();

    const int w  = tid >> 6;
    const int l  = tid & 63;
    const int ml = l & 15;
    const int q  = l >> 4;

    float4v acc[2][4];
    #pragma unroll
    for (int rt = 0; rt < 2; ++rt)
        #pragma unroll
        for (int ct = 0; ct < 4; ++ct)
            acc[rt][ct] = (float4v){0.f, 0.f, 0.f, 0.f};

    #pragma unroll
    for (int ks = 0; ks < 4; ++ks) {
        const int ko = ks * 32 + q * 8;
        short8 a0 = *(const short8*)&Fh[(w * 32 +  0 + ml) * KPF + ko];
        short8 a1 = *(const short8*)&Fh[(w * 32 + 16 + ml) * KPF + ko];
        short8 b0 = *(const short8*)&Wt[( 0 + ml) * KPW + ko];
        short8 b1 = *(const short8*)&Wt[(16 + ml) * KPW + ko];
        short8 b2 = *(const short8*)&Wt[(32 + ml) * KPW + ko];
        short8 b3 = *(const short8*)&Wt[(48 + ml) * KPW + ko];
        acc[0][0] = __builtin_amdgcn_mfma_f32_16x16x32_bf16(a0, b0, acc[0][0], 0, 0, 0);
        acc[0][1] = __builtin_amdgcn_mfma_f32_16x16x32_bf16(a0, b1, acc[0][1], 0, 0, 0);
        acc[0][2] = __builtin_amdgcn_mfma_f32_16x16x32_bf16(a0, b2, acc[0][2], 0, 0, 0);
        acc[0][3] = __builtin_amdgcn_mfma_f32_16x16x32_bf16(a0, b3, acc[0][3], 0, 0, 0);
        acc[1][0] = __builtin_amdgcn_mfma_f32_16x16x32_bf16(a1, b0, acc[1][0], 0, 0, 0);
        acc[1][1] = __builtin_amdgcn_mfma_f32_16x16x32_bf16(a1, b1, acc[1][1], 0, 0, 0);
        acc[1][2] = __builtin_amdgcn_mfma_f32_16x16x32_bf16(a1, b2, acc[1][2], 0, 0, 0);
        acc[1][3] = __builtin_amdgcn_mfma_f32_16x16x32_bf16(a1, b3, acc[1][3], 0, 0, 0);
    }

    #pragma unroll
    for (int rt = 0; rt < 2; ++rt) {
        #pragma unroll
        for (int reg = 0; reg < 4; ++reg) {
            int row = row0 + w * 32 + rt * 16 + q * 4 + reg;
            if (row < n) {
                float ns = rsqrtf(fmaxf((float)outdeg[row], 1.0f));
                #pragma unroll
                for (int ct = 0; ct < 4; ++ct)
                    h[(long)row * OUT_F + ct * 16 + ml] = __float2half(acc[rt][ct][reg] * ns);
            }
        }
    }
}

// ---- pull aggregation: out[d] = rsqrt(indeg) * sum h[src] -------------------
// one wave per dst; quarter-wave per edge (16 lanes x 8 B = full 128 B h-row),
// 2-deep unroll -> 8 h-rows in flight per wave. Register accumulation only.
__global__ __launch_bounds__(256) void gather_kernel(
    const int* __restrict__ ebuf, const int* __restrict__ off,
    const __half* __restrict__ h, float* __restrict__ out, int n)
{
    int d  = blockIdx.x * 4 + (threadIdx.x >> 6);
    int l  = threadIdx.x & 63;
    int q  = l >> 4;        // quarter-wave 0..3: edge stream
    int t  = l & 15;        // covers cols 4t..4t+3
    if (d >= n) return;
    int beg = off[d], end = off[d + 1];
    int m = end - beg;
    float4 acc = make_float4(0.f, 0.f, 0.f, 0.f);
    int j = beg + q;
    for (; j + 4 < end; j += 8) {
        int s0 = ebuf[j], s1 = ebuf[j + 4];
        __half2 p0 = *(const __half2*)&h[(long)s0 * OUT_F + 4 * t];
        __half2 p1 = *(const __half2*)&h[(long)s0 * OUT_F + 4 * t + 2];
        __half2 p2 = *(const __half2*)&h[(long)s1 * OUT_F + 4 * t];
        __half2 p3 = *(const __half2*)&h[(long)s1 * OUT_F + 4 * t + 2];
        float2 f0 = __half22float2(p0), f1 = __half22float2(p1);
        float2 f2 = __half22float2(p2), f3 = __half22float2(p3);
        acc.x += f0.x + f2.x; acc.y += f0.y + f2.y;
        acc.z += f1.x + f3.x; acc.w += f1.y + f3.y;
    }
    if (j < end) {
        int s = ebuf[j];
        __half2 p0 = *(const __half2*)&h[(long)s * OUT_F + 4 * t];
        __half2 p1 = *(const __half2*)&h[(long)s * OUT_F + 4 * t + 2];
        float2 f0 = __half22float2(p0), f1 = __half22float2(p1);
        acc.x += f0.x; acc.y += f0.y; acc.z += f1.x; acc.w += f1.y;
    }
    // butterfly-combine the 4 quarter-wave partial sums
    acc.x += __shfl_xor(acc.x, 16); acc.y += __shfl_xor(acc.y, 16);
    acc.z += __shfl_xor(acc.z, 16); acc.w += __shfl_xor(acc.w, 16);
    acc.x += __shfl_xor(acc.x, 32); acc.y += __shfl_xor(acc.y, 32);
    acc.z += __shfl_xor(acc.z, 32); acc.w += __shfl_xor(acc.w, 32);
    if (q == 0) {
        float nd = rsqrtf(fmaxf((float)m, 1.0f));
        acc.x *= nd; acc.y *= nd; acc.z *= nd; acc.w *= nd;
        *(float4*)&out[(long)d * OUT_F + 4 * t] = acc;   // 16 lanes x 16 B coalesced
    }
}

extern "C" void kernel_launch(void* const* d_in, const int* in_sizes, int n_in,
                              void* d_out, int out_size, void* d_ws, size_t ws_size,
                              hipStream_t stream) {
    const float* feat = (const float*)d_in[0];
    const float* W    = (const float*)d_in[1];
    const int*   src  = (const int*)d_in[2];
    const int*   dst  = (const int*)d_in[3];
    float* out = (float*)d_out;

    const int n = in_sizes[0] / IN_F;     // 100000
    const int E = in_sizes[2];            // 600000

    // ---- workspace layout (~22 MB, no aliasing) ----
    char* wsb = (char*)d_ws;
    int* gcur_d = (int*)wsb;                            // 256
    int* gcur_s = gcur_d + 256;                         // 256
    int* bbase  = gcur_s + 256;                         // 256
    int* outdeg = bbase + 256;                          // n
    int* off    = outdeg + n;                           // NB*512 + 1
    size_t pos = (((size_t)(4 * 256 + n + NB * 512 + 1)) * 4 + 15) & ~(size_t)15;
    unsigned* bkt_d = (unsigned*)(wsb + pos);           // NB*CAP u32 (3.93 MB)
    pos = (pos + (size_t)NB * CAP * 4 + 15) & ~(size_t)15;
    unsigned short* bkt_s = (unsigned short*)(wsb + pos); // NB*CAP u16 (1.97 MB)
    pos = (pos + (size_t)NB * CAP * 2 + 15) & ~(size_t)15;
    int* ebuf = (int*)(wsb + pos);                      // E (2.4 MB)
    pos = (pos + (size_t)E * 4 + 15) & ~(size_t)15;
    __half* h = (__half*)(wsb + pos);                   // n*64 fp16 (12.8 MB)

    hipMemsetAsync(gcur_d, 0, 2 * NB * sizeof(int), stream);

    bin_kernel<<<(E + CHUNK - 1) / CHUNK, 256, 0, stream>>>(src, dst, gcur_d, gcur_s,
                                                            bkt_d, bkt_s, E);
    base_kernel<<<1, 256, 0, stream>>>(gcur_d, bbase);
    outdeg_kernel<<<NB, 256, 0, stream>>>(bkt_s, gcur_s, outdeg, n);
    csr_kernel<<<NB, 256, 0, stream>>>(bkt_d, gcur_d, bbase, off, ebuf);
    gemm_norm_kernel<<<(n + 127) / 128, 256, 0, stream>>>(feat, W, outdeg, h, n);
    gather_kernel<<<(n + 3) / 4, 256, 0, stream>>>(ebuf, off, h, out, n);
}